// Round 1
// baseline (170.071 us; speedup 1.0000x reference)
//
#include <hip/hip_runtime.h>

// Discounted cumsum along S for x:(B,H,S,D)=(8,16,4096,128) fp32, gamma:(H,)
// y[t] = x[t] + gamma[h]*y[t-1].
// 3-phase chunked scan: chunk-ends reduce -> carry scan -> apply.

namespace {
constexpr int kH   = 16;
constexpr int kBH  = 128;        // B*H
constexpr int kS   = 4096;
constexpr int kD   = 128;
constexpr int kD4  = kD / 4;     // 32 float4 per row
constexpr int kC   = 64;         // chunks along S
constexpr int kL   = kS / kC;    // 64 timesteps per chunk
constexpr int kThreads = 256;
}

// K1: per-(bh, chunk, d4) local scan; emit end value (carry assuming 0 in).
__global__ __launch_bounds__(kThreads) void k1_chunk_ends(
    const float* __restrict__ x, const float* __restrict__ gamma,
    float4* __restrict__ ends)
{
    int tid = blockIdx.x * kThreads + threadIdx.x;   // [0, kBH*kC*kD4)
    int d4 = tid & (kD4 - 1);
    int c  = (tid >> 5) & (kC - 1);
    int bh = tid >> 11;
    float g = gamma[bh & (kH - 1)];
    const float4* xv = reinterpret_cast<const float4*>(x);
    int base = (bh * kS + c * kL) * kD4 + d4;
    float4 acc = make_float4(0.f, 0.f, 0.f, 0.f);
    #pragma unroll 8
    for (int i = 0; i < kL; ++i) {
        float4 v = xv[base + i * kD4];
        acc.x = fmaf(g, acc.x, v.x);
        acc.y = fmaf(g, acc.y, v.y);
        acc.z = fmaf(g, acc.z, v.z);
        acc.w = fmaf(g, acc.w, v.w);
    }
    ends[tid] = acc;
}

// K2: in-place serial scan over the kC chunk ends per (bh, d4) chain.
// After this, ends[(bh, c, d4)] holds the carry INTO chunk c (y at t=c*L-1).
__global__ __launch_bounds__(kThreads) void k2_carry_scan(
    float4* __restrict__ ends, const float* __restrict__ gamma)
{
    int tid = blockIdx.x * kThreads + threadIdx.x;   // [0, kBH*kD4)
    int d4 = tid & (kD4 - 1);
    int bh = tid >> 5;
    float g = gamma[bh & (kH - 1)];
    float gl = g;
    #pragma unroll
    for (int k = 0; k < 6; ++k) gl *= gl;            // g^64 == g^kL
    float4 prev = make_float4(0.f, 0.f, 0.f, 0.f);   // carry into chunk 0
    for (int c = 0; c < kC; ++c) {
        int idx = (bh * kC + c) * kD4 + d4;
        float4 cur = ends[idx];
        ends[idx] = prev;
        // full_end[c] = local_end[c] + g^L * full_end[c-1]
        prev.x = fmaf(gl, prev.x, cur.x);
        prev.y = fmaf(gl, prev.y, cur.y);
        prev.z = fmaf(gl, prev.z, cur.z);
        prev.w = fmaf(gl, prev.w, cur.w);
    }
}

// K3: re-read x, seed accumulator with carry-in, write final y.
__global__ __launch_bounds__(kThreads) void k3_apply(
    const float* __restrict__ x, const float* __restrict__ gamma,
    const float4* __restrict__ carry, float* __restrict__ y)
{
    int tid = blockIdx.x * kThreads + threadIdx.x;   // [0, kBH*kC*kD4)
    int d4 = tid & (kD4 - 1);
    int c  = (tid >> 5) & (kC - 1);
    int bh = tid >> 11;
    float g = gamma[bh & (kH - 1)];
    const float4* xv = reinterpret_cast<const float4*>(x);
    float4* yv = reinterpret_cast<float4*>(y);
    int base = (bh * kS + c * kL) * kD4 + d4;
    float4 acc = carry[tid];
    #pragma unroll 8
    for (int i = 0; i < kL; ++i) {
        float4 v = xv[base + i * kD4];
        acc.x = fmaf(g, acc.x, v.x);
        acc.y = fmaf(g, acc.y, v.y);
        acc.z = fmaf(g, acc.z, v.z);
        acc.w = fmaf(g, acc.w, v.w);
        yv[base + i * kD4] = acc;
    }
}

extern "C" void kernel_launch(void* const* d_in, const int* in_sizes, int n_in,
                              void* d_out, int out_size, void* d_ws, size_t ws_size,
                              hipStream_t stream) {
    const float* x     = (const float*)d_in[0];
    const float* gamma = (const float*)d_in[1];
    float* y = (float*)d_out;
    float4* ends = (float4*)d_ws;   // kBH*kC*kD4 float4 = 4 MiB

    int total = kBH * kC * kD4;     // 262144 threads
    int blocks = total / kThreads;  // 1024
    k1_chunk_ends<<<blocks, kThreads, 0, stream>>>(x, gamma, ends);

    int total2 = kBH * kD4;         // 4096 threads
    k2_carry_scan<<<total2 / kThreads, kThreads, 0, stream>>>(ends, gamma);

    k3_apply<<<blocks, kThreads, 0, stream>>>(x, gamma, ends, y);
}

// Round 2
// 108.522 us; speedup vs baseline: 1.5672x; 1.5672x over previous
//
#include <hip/hip_runtime.h>

// Discounted cumsum y[t] = x[t] + gamma[h]*y[t-1] along S.
// x:(B,H,S,D)=(8,16,4096,128) fp32, gamma:(H,)
// Single-pass: block = (bh, D-half), walks S in 32 tiles of 128 timesteps.
// Per tile: thread-serial scan of 8 t's + intra-wave shfl scan + LDS wave
// combine + double-buffered LDS carry (1 barrier per tile).

namespace {
constexpr int kH     = 16;
constexpr int kBH    = 128;       // B*H
constexpr int kS     = 4096;
constexpr int kD4    = 32;        // float4 per row (D=128)
constexpr int kDH4   = 16;        // float4 columns per block (half of D)
constexpr int kTG    = 16;        // thread-groups along t per tile
constexpr int kJ     = 8;         // timesteps per thread
constexpr int kTileT = kTG * kJ;  // 128 timesteps per tile
constexpr int kIters = kS / kTileT; // 32
constexpr int kThreads = kDH4 * kTG; // 256
}

__global__ __launch_bounds__(kThreads) void dscan_kernel(
    const float* __restrict__ x, const float* __restrict__ gamma,
    float* __restrict__ y)
{
    const int bh    = blockIdx.x >> 1;
    const int dhalf = blockIdx.x & 1;
    const int tid   = (int)threadIdx.x;
    const int d4c   = tid & (kDH4 - 1);
    const int tg    = tid >> 4;      // 0..15, timestep group
    const int wv    = tg >> 2;       // wave id 0..3
    const int tgl   = tg & 3;        // tg within wave

    const float g = gamma[bh & (kH - 1)];
    float gp[kJ];                    // gp[j] = g^(j+1)
    gp[0] = g;
    #pragma unroll
    for (int j = 1; j < kJ; ++j) gp[j] = gp[j - 1] * g;
    const float g8  = gp[kJ - 1];    // g^8
    const float g16 = g8 * g8;
    const float g32 = g16 * g16;
    // gtl = g8^tgl ; g8tg = g^(8*tg) = g8^tgl * g32^wv
    const float gtl = (tgl == 0) ? 1.f : ((tgl == 1) ? g8 : ((tgl == 2) ? g16 : g16 * g8));
    float g8tg = gtl;
    #pragma unroll
    for (int i = 0; i < 3; ++i) g8tg = (wv > i) ? g8tg * g32 : g8tg;

    __shared__ float4 s_wsum[2][4][kDH4];   // [parity][wave][d4c]
    __shared__ float4 s_carry[2][kDH4];     // [parity][d4c]
    if (tid < kDH4) s_carry[0][tid] = make_float4(0.f, 0.f, 0.f, 0.f);
    __syncthreads();

    const float4* __restrict__ xv = reinterpret_cast<const float4*>(x);
    float4*       __restrict__ yv = reinterpret_cast<float4*>(y);
    const int base = bh * kS * kD4 + dhalf * kDH4 + d4c;
    const int tb   = tg * kJ;

    float4 v[kJ], w[kJ];
    #pragma unroll
    for (int j = 0; j < kJ; ++j) v[j] = xv[base + (tb + j) * kD4];

    for (int it = 0; it < kIters; ++it) {
        const int p = it & 1;

        // local inclusive scan over this thread's 8 timesteps
        #pragma unroll
        for (int j = 1; j < kJ; ++j) {
            v[j].x = fmaf(g, v[j - 1].x, v[j].x);
            v[j].y = fmaf(g, v[j - 1].y, v[j].y);
            v[j].z = fmaf(g, v[j - 1].z, v[j].z);
            v[j].w = fmaf(g, v[j - 1].w, v[j].w);
        }

        // prefetch next tile while we do the cross-thread combine
        if (it + 1 < kIters) {
            const int nb = base + ((it + 1) * kTileT + tb) * kD4;
            #pragma unroll
            for (int j = 0; j < kJ; ++j) w[j] = xv[nb + j * kD4];
        }

        // intra-wave inclusive scan of thread totals (4 tgs per wave)
        float4 s = v[kJ - 1];
        {
            float tx = __shfl_up(s.x, 16, 64);
            float ty = __shfl_up(s.y, 16, 64);
            float tz = __shfl_up(s.z, 16, 64);
            float tw = __shfl_up(s.w, 16, 64);
            if (tgl >= 1) {
                s.x = fmaf(g8, tx, s.x);
                s.y = fmaf(g8, ty, s.y);
                s.z = fmaf(g8, tz, s.z);
                s.w = fmaf(g8, tw, s.w);
            }
        }
        {
            float tx = __shfl_up(s.x, 32, 64);
            float ty = __shfl_up(s.y, 32, 64);
            float tz = __shfl_up(s.z, 32, 64);
            float tw = __shfl_up(s.w, 32, 64);
            if (tgl >= 2) {
                s.x = fmaf(g16, tx, s.x);
                s.y = fmaf(g16, ty, s.y);
                s.z = fmaf(g16, tz, s.z);
                s.w = fmaf(g16, tw, s.w);
            }
        }
        // exclusive prefix within wave (y at this thread's start-1, wave-local)
        float4 X;
        X.x = __shfl_up(s.x, 16, 64);
        X.y = __shfl_up(s.y, 16, 64);
        X.z = __shfl_up(s.z, 16, 64);
        X.w = __shfl_up(s.w, 16, 64);
        if (tgl == 0) X = make_float4(0.f, 0.f, 0.f, 0.f);

        if (tgl == 3) s_wsum[p][wv][d4c] = s;   // wave total per column
        __syncthreads();

        // combine: C = scan of earlier waves' totals (decay g32 per wave)
        float4 C = make_float4(0.f, 0.f, 0.f, 0.f);
        #pragma unroll
        for (int w2 = 0; w2 < 3; ++w2) {
            if (w2 < wv) {
                float4 W = s_wsum[p][w2][d4c];
                C.x = fmaf(g32, C.x, W.x);
                C.y = fmaf(g32, C.y, W.y);
                C.z = fmaf(g32, C.z, W.z);
                C.w = fmaf(g32, C.w, W.w);
            }
        }
        const float4 A = s_carry[p][d4c];       // y at tile_start - 1
        float4 E;                               // y at this thread's start-1
        E.x = fmaf(g8tg, A.x, fmaf(gtl, C.x, X.x));
        E.y = fmaf(g8tg, A.y, fmaf(gtl, C.y, X.y));
        E.z = fmaf(g8tg, A.z, fmaf(gtl, C.z, X.z));
        E.w = fmaf(g8tg, A.w, fmaf(gtl, C.w, X.w));

        // apply prefix and store
        const int ob = base + (it * kTileT + tb) * kD4;
        #pragma unroll
        for (int j = 0; j < kJ; ++j) {
            float4 o;
            o.x = fmaf(gp[j], E.x, v[j].x);
            o.y = fmaf(gp[j], E.y, v[j].y);
            o.z = fmaf(gp[j], E.z, v[j].z);
            o.w = fmaf(gp[j], E.w, v[j].w);
            yv[ob + j * kD4] = o;
            if (j == kJ - 1 && tg == kTG - 1) s_carry[p ^ 1][d4c] = o;
        }

        // rotate prefetched registers
        #pragma unroll
        for (int j = 0; j < kJ; ++j) v[j] = w[j];
    }
}

extern "C" void kernel_launch(void* const* d_in, const int* in_sizes, int n_in,
                              void* d_out, int out_size, void* d_ws, size_t ws_size,
                              hipStream_t stream) {
    const float* x     = (const float*)d_in[0];
    const float* gamma = (const float*)d_in[1];
    float* y = (float*)d_out;
    dscan_kernel<<<kBH * 2, kThreads, 0, stream>>>(x, gamma, y);
}

// Round 3
// 107.241 us; speedup vs baseline: 1.5859x; 1.0119x over previous
//
#include <hip/hip_runtime.h>

// Discounted cumsum y[t] = x[t] + gamma[h]*y[t-1] along S.
// x:(B,H,S,D)=(8,16,4096,128) fp32, gamma:(H,)
// Single-pass: block = (bh, D-quarter: 8 float4 cols), 256 threads,
// walks S in 16 tiles of 256 timesteps. Per tile: thread-serial scan of
// 8 t's + 3-step shfl scan over 8 tgs/wave + LDS 4-wave combine +
// double-buffered carry, ONE lgkm-only barrier per tile (loads/stores
// ride across; vmcnt never force-drained at barriers).

namespace {
constexpr int kH     = 16;
constexpr int kBH    = 128;         // B*H
constexpr int kS     = 4096;
constexpr int kD4    = 32;          // float4 per row (D=128)
constexpr int kDQ4   = 8;           // float4 columns per block (quarter of D)
constexpr int kTG    = 32;          // thread-groups along t per tile
constexpr int kJ     = 8;           // timesteps per thread
constexpr int kTileT = kTG * kJ;    // 256 timesteps per tile
constexpr int kIters = kS / kTileT; // 16
constexpr int kThreads = kDQ4 * kTG; // 256
}

__global__ __launch_bounds__(kThreads) void dscan_kernel(
    const float* __restrict__ x, const float* __restrict__ gamma,
    float* __restrict__ y)
{
    const int bh = blockIdx.x >> 2;
    const int dq = blockIdx.x & 3;
    const int tid = (int)threadIdx.x;
    const int d4c = tid & (kDQ4 - 1);
    const int tg  = tid >> 3;        // 0..31 timestep group
    const int wv  = tg >> 3;         // wave id 0..3
    const int tgl = tg & 7;          // tg within wave

    const float g = gamma[bh & (kH - 1)];
    float gp[kJ];                    // gp[j] = g^(j+1)
    gp[0] = g;
    #pragma unroll
    for (int j = 1; j < kJ; ++j) gp[j] = gp[j - 1] * g;
    const float g8   = gp[kJ - 1];   // g^8
    const float g16  = g8 * g8;
    const float g32  = g16 * g16;
    const float g64  = g32 * g32;    // per-wave decay (8 tgs * 8 t)
    const float g128 = g64 * g64;
    // gtl = g^(8*tgl); g8tg = g^(8*tg)
    const float gtl = ((tgl & 1) ? g8 : 1.f) * ((tgl & 2) ? g16 : 1.f) *
                      ((tgl & 4) ? g32 : 1.f);
    const float g8tg = gtl * ((tg & 8) ? g64 : 1.f) * ((tg & 16) ? g128 : 1.f);

    __shared__ float4 s_wsum[2][4][kDQ4];   // [parity][wave][d4c]
    __shared__ float4 s_carry[2][kDQ4];     // [parity][d4c]
    if (tid < kDQ4) s_carry[0][tid] = make_float4(0.f, 0.f, 0.f, 0.f);
    __syncthreads();

    const float4* __restrict__ xv = reinterpret_cast<const float4*>(x);
    float4*       __restrict__ yv = reinterpret_cast<float4*>(y);
    const int base = bh * kS * kD4 + dq * kDQ4 + d4c;
    const int tb   = tg * kJ;

    float4 v[kJ], w[kJ];
    #pragma unroll
    for (int j = 0; j < kJ; ++j) v[j] = xv[base + (tb + j) * kD4];

    auto tile = [&](int it, float4 (&cv)[kJ], float4 (&nv)[kJ]) {
        const int p = it & 1;

        // local inclusive scan over this thread's 8 timesteps
        #pragma unroll
        for (int j = 1; j < kJ; ++j) {
            cv[j].x = fmaf(g, cv[j - 1].x, cv[j].x);
            cv[j].y = fmaf(g, cv[j - 1].y, cv[j].y);
            cv[j].z = fmaf(g, cv[j - 1].z, cv[j].z);
            cv[j].w = fmaf(g, cv[j - 1].w, cv[j].w);
        }

        // prefetch next tile (rides across the lgkm-only barrier)
        if (it + 1 < kIters) {
            const int nb = base + ((it + 1) * kTileT + tb) * kD4;
            #pragma unroll
            for (int j = 0; j < kJ; ++j) nv[j] = xv[nb + j * kD4];
        }

        // intra-wave inclusive scan of thread totals (8 tgs, stride 8 lanes)
        float4 s = cv[kJ - 1];
        {
            float tx = __shfl_up(s.x, 8, 64), ty = __shfl_up(s.y, 8, 64);
            float tz = __shfl_up(s.z, 8, 64), tw = __shfl_up(s.w, 8, 64);
            if (tgl >= 1) {
                s.x = fmaf(g8, tx, s.x); s.y = fmaf(g8, ty, s.y);
                s.z = fmaf(g8, tz, s.z); s.w = fmaf(g8, tw, s.w);
            }
        }
        {
            float tx = __shfl_up(s.x, 16, 64), ty = __shfl_up(s.y, 16, 64);
            float tz = __shfl_up(s.z, 16, 64), tw = __shfl_up(s.w, 16, 64);
            if (tgl >= 2) {
                s.x = fmaf(g16, tx, s.x); s.y = fmaf(g16, ty, s.y);
                s.z = fmaf(g16, tz, s.z); s.w = fmaf(g16, tw, s.w);
            }
        }
        {
            float tx = __shfl_up(s.x, 32, 64), ty = __shfl_up(s.y, 32, 64);
            float tz = __shfl_up(s.z, 32, 64), tw = __shfl_up(s.w, 32, 64);
            if (tgl >= 4) {
                s.x = fmaf(g32, tx, s.x); s.y = fmaf(g32, ty, s.y);
                s.z = fmaf(g32, tz, s.z); s.w = fmaf(g32, tw, s.w);
            }
        }
        // exclusive wave-local prefix at this thread's start-1
        float4 X;
        X.x = __shfl_up(s.x, 8, 64); X.y = __shfl_up(s.y, 8, 64);
        X.z = __shfl_up(s.z, 8, 64); X.w = __shfl_up(s.w, 8, 64);
        if (tgl == 0) X = make_float4(0.f, 0.f, 0.f, 0.f);

        if (tgl == 7) s_wsum[p][wv][d4c] = s;   // wave total per column

        // LDS-only drain + barrier: vmem ops stay in flight
        asm volatile("s_waitcnt lgkmcnt(0)\n\ts_barrier" ::: "memory");

        // combine earlier waves' totals (decay g64 per wave)
        float4 C = make_float4(0.f, 0.f, 0.f, 0.f);
        #pragma unroll
        for (int w2 = 0; w2 < 3; ++w2) {
            if (w2 < wv) {
                float4 W = s_wsum[p][w2][d4c];
                C.x = fmaf(g64, C.x, W.x); C.y = fmaf(g64, C.y, W.y);
                C.z = fmaf(g64, C.z, W.z); C.w = fmaf(g64, C.w, W.w);
            }
        }
        const float4 A = s_carry[p][d4c];       // y at tile_start - 1
        float4 E;                               // y at this thread's start-1
        E.x = fmaf(g8tg, A.x, fmaf(gtl, C.x, X.x));
        E.y = fmaf(g8tg, A.y, fmaf(gtl, C.y, X.y));
        E.z = fmaf(g8tg, A.z, fmaf(gtl, C.z, X.z));
        E.w = fmaf(g8tg, A.w, fmaf(gtl, C.w, X.w));

        // apply prefix and store
        const int ob = base + (it * kTileT + tb) * kD4;
        #pragma unroll
        for (int j = 0; j < kJ; ++j) {
            float4 o;
            o.x = fmaf(gp[j], E.x, cv[j].x);
            o.y = fmaf(gp[j], E.y, cv[j].y);
            o.z = fmaf(gp[j], E.z, cv[j].z);
            o.w = fmaf(gp[j], E.w, cv[j].w);
            yv[ob + j * kD4] = o;
            if (j == kJ - 1 && tg == kTG - 1) s_carry[p ^ 1][d4c] = o;
        }
    };

    for (int it = 0; it < kIters; it += 2) {
        tile(it, v, w);
        tile(it + 1, w, v);
    }
}

extern "C" void kernel_launch(void* const* d_in, const int* in_sizes, int n_in,
                              void* d_out, int out_size, void* d_ws, size_t ws_size,
                              hipStream_t stream) {
    const float* x     = (const float*)d_in[0];
    const float* gamma = (const float*)d_in[1];
    float* y = (float*)d_out;
    dscan_kernel<<<kBH * 4, kThreads, 0, stream>>>(x, gamma, y);
}